// Round 1
// baseline (977.313 us; speedup 1.0000x reference)
//
#include <hip/hip_runtime.h>
#include <math.h>

// ---------------------------------------------------------------------------
// GCN link predictor on MI355X. Pipeline:
//   deg/dinv -> CSR (hist + scan + scatter) -> GEMM1 -> agg+BN+ReLU ->
//   GEMM2 -> agg+BN+ReLU -> edge-head MLP (fused gather+GEMM+sigmoid)
// Round 1: all fp32 vector ALU, no atomic float accumulation (CSR gather).
// ---------------------------------------------------------------------------

__global__ void zero_int_kernel(int* __restrict__ p, int n) {
  int i = blockIdx.x * blockDim.x + threadIdx.x;
  if (i < n) p[i] = 0;
}

__global__ void degree_hist_kernel(const int* __restrict__ col, int* __restrict__ deg, int E) {
  int i = blockIdx.x * blockDim.x + threadIdx.x;
  if (i < E) atomicAdd(&deg[col[i]], 1);
}

__global__ void dinv_kernel(const int* __restrict__ deg, float* __restrict__ dinv, int n) {
  int i = blockIdx.x * blockDim.x + threadIdx.x;
  if (i < n) dinv[i] = rsqrtf((float)deg[i] + 1.0f);
}

// Single-block exclusive scan over n ints (n ~ 50000). 1024 threads, wave scans
// via shfl, 16 wave-sums scanned by wave 0, running carry across 1024-chunks.
__global__ __launch_bounds__(1024) void scan_exclusive_kernel(const int* __restrict__ deg,
                                                              int* __restrict__ offs, int n) {
  __shared__ int wsum[16];
  __shared__ int carry_s;
  const int tid = threadIdx.x;
  const int lane = tid & 63;
  const int wid = tid >> 6;
  if (tid == 0) carry_s = 0;
  __syncthreads();
  for (int base = 0; base < n; base += 1024) {
    int i = base + tid;
    int v = (i < n) ? deg[i] : 0;
    int incl = v;
#pragma unroll
    for (int d = 1; d < 64; d <<= 1) {
      int t = __shfl_up(incl, d, 64);
      if (lane >= d) incl += t;
    }
    if (lane == 63) wsum[wid] = incl;
    __syncthreads();
    if (wid == 0) {
      int sv = (lane < 16) ? wsum[lane] : 0;
#pragma unroll
      for (int d = 1; d < 16; d <<= 1) {
        int t = __shfl_up(sv, d, 64);
        if (lane >= d) sv += t;
      }
      if (lane < 16) wsum[lane] = sv;
    }
    __syncthreads();
    int woff = (wid > 0) ? wsum[wid - 1] : 0;
    int excl = woff + incl - v;
    int carry = carry_s;
    if (i < n) offs[i] = carry + excl;
    __syncthreads();
    if (tid == 1023) carry_s = carry + excl + v;  // carry + block total
    __syncthreads();
  }
  if (tid == 0) offs[n] = carry_s;
}

__global__ void copy_int_kernel(const int* __restrict__ a, int* __restrict__ b, int n) {
  int i = blockIdx.x * blockDim.x + threadIdx.x;
  if (i < n) b[i] = a[i];
}

__global__ void scatter_kernel(const int* __restrict__ row, const int* __restrict__ col,
                               int* __restrict__ cursor, int* __restrict__ csr_row, int E) {
  int i = blockIdx.x * blockDim.x + threadIdx.x;
  if (i < E) {
    int c = col[i];
    int p = atomicAdd(&cursor[c], 1);
    csr_row[p] = row[i];
  }
}

// Tiled fp32 GEMM: C[M,N] = A[M,K] @ B[K,N]. 256 threads, TN fixed = 4.
template <int BM, int BN, int BK, int TM>
__global__ __launch_bounds__(256) void gemm_kernel(const float* __restrict__ A,
                                                   const float* __restrict__ B,
                                                   float* __restrict__ C, int M, int K, int N) {
  constexpr int TN = 4;
  constexpr int NT = (BM / TM) * (BN / TN);
  static_assert(NT == 256, "block must be 256 threads");
  __shared__ float As[BM][BK + 4];
  __shared__ float Bs[BK][BN];
  const int tid = threadIdx.x;
  const int tx = tid % (BN / TN);
  const int ty = tid / (BN / TN);
  const int m0 = blockIdx.x * BM;
  float acc[TM][TN];
#pragma unroll
  for (int r = 0; r < TM; ++r)
#pragma unroll
    for (int c = 0; c < TN; ++c) acc[r][c] = 0.f;

  for (int k0 = 0; k0 < K; k0 += BK) {
    for (int t = tid; t < BM * BK / 4; t += NT) {
      int m = t / (BK / 4), kq = t % (BK / 4);
      int r = m0 + m;
      if (r >= M) r = M - 1;
      float4 v = *(const float4*)(A + (size_t)r * K + k0 + kq * 4);
      *(float4*)(&As[m][kq * 4]) = v;
    }
    for (int t = tid; t < BK * BN / 4; t += NT) {
      int kk = t / (BN / 4), nq = t % (BN / 4);
      float4 v = *(const float4*)(B + (size_t)(k0 + kk) * N + nq * 4);
      *(float4*)(&Bs[kk][nq * 4]) = v;
    }
    __syncthreads();
#pragma unroll
    for (int kk = 0; kk < BK; kk += 4) {
      float4 a4[TM];
#pragma unroll
      for (int r = 0; r < TM; ++r) a4[r] = *(const float4*)(&As[ty * TM + r][kk]);
      float4 b0 = *(const float4*)(&Bs[kk + 0][tx * TN]);
      float4 b1 = *(const float4*)(&Bs[kk + 1][tx * TN]);
      float4 b2 = *(const float4*)(&Bs[kk + 2][tx * TN]);
      float4 b3 = *(const float4*)(&Bs[kk + 3][tx * TN]);
#pragma unroll
      for (int r = 0; r < TM; ++r) {
        acc[r][0] += a4[r].x * b0.x + a4[r].y * b1.x + a4[r].z * b2.x + a4[r].w * b3.x;
        acc[r][1] += a4[r].x * b0.y + a4[r].y * b1.y + a4[r].z * b2.y + a4[r].w * b3.y;
        acc[r][2] += a4[r].x * b0.z + a4[r].y * b1.z + a4[r].z * b2.z + a4[r].w * b3.z;
        acc[r][3] += a4[r].x * b0.w + a4[r].y * b1.w + a4[r].z * b2.w + a4[r].w * b3.w;
      }
    }
    __syncthreads();
  }
#pragma unroll
  for (int r = 0; r < TM; ++r) {
    int row = m0 + ty * TM + r;
    if (row < M) {
      float4 v = make_float4(acc[r][0], acc[r][1], acc[r][2], acc[r][3]);
      *(float4*)(C + (size_t)row * N + tx * TN) = v;
    }
  }
}

// One block per node, F threads (feature per thread). CSR gather aggregation,
// fused self-loop + bias + BN(eval) + ReLU.
template <int F>
__global__ void agg_bn_relu_kernel(const float* __restrict__ xw, const int* __restrict__ offs,
                                   const int* __restrict__ rows, const float* __restrict__ dinv,
                                   const float* __restrict__ bias, const float* __restrict__ gamma,
                                   const float* __restrict__ beta, const float* __restrict__ mean,
                                   const float* __restrict__ var, float* __restrict__ out) {
  const int i = blockIdx.x;
  const int f = threadIdx.x;
  const float di = dinv[i];
  const int s = offs[i], e = offs[i + 1];
  float acc = 0.f;
  int t = s;
  for (; t + 4 <= e; t += 4) {
    int r0 = rows[t], r1 = rows[t + 1], r2 = rows[t + 2], r3 = rows[t + 3];
    float w0 = dinv[r0], w1 = dinv[r1], w2 = dinv[r2], w3 = dinv[r3];
    acc += w0 * xw[(size_t)r0 * F + f] + w1 * xw[(size_t)r1 * F + f] +
           w2 * xw[(size_t)r2 * F + f] + w3 * xw[(size_t)r3 * F + f];
  }
  for (; t < e; ++t) {
    int r = rows[t];
    acc += dinv[r] * xw[(size_t)r * F + f];
  }
  float v = di * acc + di * di * xw[(size_t)i * F + f] + bias[f];
  v = (v - mean[f]) * rsqrtf(var[f] + 1e-5f) * gamma[f] + beta[f];
  out[(size_t)i * F + f] = fmaxf(v, 0.f);
}

__global__ void transpose_w_kernel(const float* __restrict__ w, float* __restrict__ wt) {
  int idx = blockIdx.x * blockDim.x + threadIdx.x;  // 128*64
  if (idx < 128 * 64) {
    int k = idx >> 6, j = idx & 63;
    wt[j * 128 + k] = w[idx];
  }
}

// Edge head: thread-per-pair. Pair (z[src]||z[dst]) in 32 float4 VGPRs;
// hW1^T rows broadcast from LDS (wave-uniform address -> conflict-free).
__global__ __launch_bounds__(256) void head_kernel(const float* __restrict__ z,
                                                   const int* __restrict__ src,
                                                   const int* __restrict__ dst,
                                                   const float* __restrict__ w1t,
                                                   const float* __restrict__ hb1,
                                                   const float* __restrict__ hw2,
                                                   const float* __restrict__ hb2,
                                                   float* __restrict__ out, int P) {
  __shared__ float4 sw[64 * 32];  // hW1T[j][k] as float4, 32 KiB
  __shared__ float sw2[64], sb1[64];
  const float4* w4 = (const float4*)w1t;
  for (int t = threadIdx.x; t < 64 * 32; t += 256) sw[t] = w4[t];
  if (threadIdx.x < 64) {
    sw2[threadIdx.x] = hw2[threadIdx.x];
    sb1[threadIdx.x] = hb1[threadIdx.x];
  }
  __syncthreads();
  int p = blockIdx.x * blockDim.x + threadIdx.x;
  if (p >= P) return;
  int s = src[p], d = dst[p];
  float4 pr[32];
  const float4* zs = (const float4*)(z + (size_t)s * 64);
  const float4* zd = (const float4*)(z + (size_t)d * 64);
#pragma unroll
  for (int q = 0; q < 16; ++q) pr[q] = zs[q];
#pragma unroll
  for (int q = 0; q < 16; ++q) pr[16 + q] = zd[q];
  float logit = hb2[0];
#pragma unroll 2
  for (int j = 0; j < 64; ++j) {
    float acc = sb1[j];
    const float4* wj = &sw[j * 32];
#pragma unroll
    for (int q = 0; q < 32; ++q) {
      float4 wv = wj[q];
      acc += pr[q].x * wv.x + pr[q].y * wv.y + pr[q].z * wv.z + pr[q].w * wv.w;
    }
    logit += fmaxf(acc, 0.f) * sw2[j];
  }
  out[p] = 1.0f / (1.0f + __expf(-logit));
}

extern "C" void kernel_launch(void* const* d_in, const int* in_sizes, int n_in,
                              void* d_out, int out_size, void* d_ws, size_t ws_size,
                              hipStream_t stream) {
  const float* x = (const float*)d_in[0];
  const int* ei = (const int*)d_in[1];
  const int* src = (const int*)d_in[2];
  const int* dst = (const int*)d_in[3];
  const float* W1 = (const float*)d_in[4];
  const float* b1 = (const float*)d_in[5];
  const float* g1 = (const float*)d_in[6];
  const float* be1 = (const float*)d_in[7];
  const float* mu1 = (const float*)d_in[8];
  const float* va1 = (const float*)d_in[9];
  const float* W2 = (const float*)d_in[10];
  const float* b2 = (const float*)d_in[11];
  const float* g2 = (const float*)d_in[12];
  const float* be2 = (const float*)d_in[13];
  const float* mu2 = (const float*)d_in[14];
  const float* va2 = (const float*)d_in[15];
  const float* hW1 = (const float*)d_in[16];
  const float* hb1 = (const float*)d_in[17];
  const float* hW2 = (const float*)d_in[18];
  const float* hb2 = (const float*)d_in[19];
  float* out = (float*)d_out;

  const int N = in_sizes[0] / 512;
  const int E = in_sizes[1] / 2;
  const int P = in_sizes[2];
  const int* row = ei;
  const int* col = ei + E;

  char* wp = (char*)d_ws;
  auto alloc = [&](size_t bytes) {
    char* p = wp;
    wp += (bytes + 255) & ~(size_t)255;
    return p;
  };
  float* xw1 = (float*)alloc((size_t)N * 128 * 4);
  float* h = (float*)alloc((size_t)N * 128 * 4);
  float* xw2 = (float*)alloc((size_t)N * 64 * 4);
  float* z = (float*)alloc((size_t)N * 64 * 4);
  float* dinv = (float*)alloc((size_t)N * 4);
  int* deg = (int*)alloc((size_t)N * 4);
  int* offs = (int*)alloc((size_t)(N + 1) * 4);
  int* cursor = (int*)alloc((size_t)N * 4);
  int* csr_row = (int*)alloc((size_t)E * 4);
  float* w1t = (float*)alloc(128 * 64 * 4);
  (void)ws_size;
  (void)n_in;
  (void)out_size;

  // --- graph structure (recomputed every call; ws is re-poisoned) ---
  hipLaunchKernelGGL(zero_int_kernel, dim3((N + 255) / 256), dim3(256), 0, stream, deg, N);
  hipLaunchKernelGGL(degree_hist_kernel, dim3((E + 255) / 256), dim3(256), 0, stream, col, deg, E);
  hipLaunchKernelGGL(dinv_kernel, dim3((N + 255) / 256), dim3(256), 0, stream, deg, dinv, N);
  hipLaunchKernelGGL(scan_exclusive_kernel, dim3(1), dim3(1024), 0, stream, deg, offs, N);
  hipLaunchKernelGGL(copy_int_kernel, dim3((N + 255) / 256), dim3(256), 0, stream, offs, cursor, N);
  hipLaunchKernelGGL(scatter_kernel, dim3((E + 255) / 256), dim3(256), 0, stream, row, col, cursor,
                     csr_row, E);
  hipLaunchKernelGGL(transpose_w_kernel, dim3(32), dim3(256), 0, stream, hW1, w1t);

  // --- layer 1 ---
  hipLaunchKernelGGL((gemm_kernel<64, 128, 16, 8>), dim3((N + 63) / 64), dim3(256), 0, stream, x,
                     W1, xw1, N, 512, 128);
  hipLaunchKernelGGL((agg_bn_relu_kernel<128>), dim3(N), dim3(128), 0, stream, xw1, offs, csr_row,
                     dinv, b1, g1, be1, mu1, va1, h);

  // --- layer 2 ---
  hipLaunchKernelGGL((gemm_kernel<64, 64, 16, 4>), dim3((N + 63) / 64), dim3(256), 0, stream, h, W2,
                     xw2, N, 128, 64);
  hipLaunchKernelGGL((agg_bn_relu_kernel<64>), dim3(N), dim3(64), 0, stream, xw2, offs, csr_row,
                     dinv, b2, g2, be2, mu2, va2, z);

  // --- edge head ---
  hipLaunchKernelGGL(head_kernel, dim3((P + 255) / 256), dim3(256), 0, stream, z, src, dst, w1t,
                     hb1, hW2, hb2, out, P);
}

// Round 2
// 612.559 us; speedup vs baseline: 1.5955x; 1.5955x over previous
//
#include <hip/hip_runtime.h>
#include <math.h>

// ---------------------------------------------------------------------------
// GCN link predictor on MI355X, round 2: bf16 MFMA for all GEMM-shaped work.
//   deg/dinv -> CSR (hist + scan + scatter)
//   prep: weights -> MFMA-B-fragment-ordered bf16
//   gemm1 (x fp32 @ W1) -> xw1 bf16 -> agg+BN+ReLU -> h bf16
//   gemm2 (h bf16 @ W2) -> xw2 bf16 -> agg+BN+ReLU -> z bf16
//   head: gather z[src]||z[dst], MFMA vs hW1, relu, dot hW2, sigmoid
// MFMA 16x16x32_bf16 layouts (HW-verified per guide):
//   A[m=lane&15][k=(lane>>4)*8+j], B[k=(lane>>4)*8+j][n=lane&15],
//   C/D: col=lane&15, row=(lane>>4)*4+reg
// ---------------------------------------------------------------------------

typedef __attribute__((ext_vector_type(8))) short short8x;
typedef __attribute__((ext_vector_type(4))) float f32x4;

__device__ __forceinline__ unsigned short f2bf(float f) {
  unsigned int u = __float_as_uint(f);
  unsigned int r = u + 0x7FFFu + ((u >> 16) & 1u);  // RNE
  return (unsigned short)(r >> 16);
}
__device__ __forceinline__ float bf2f(unsigned short u) {
  return __uint_as_float(((unsigned int)u) << 16);
}

// ------------------------------ graph build --------------------------------

__global__ void zero_int_kernel(int* __restrict__ p, int n) {
  int i = blockIdx.x * blockDim.x + threadIdx.x;
  if (i < n) p[i] = 0;
}

__global__ void degree_hist_kernel(const int* __restrict__ col, int* __restrict__ deg, int E) {
  int i = blockIdx.x * blockDim.x + threadIdx.x;
  if (i < E) atomicAdd(&deg[col[i]], 1);
}

__global__ void dinv_kernel(const int* __restrict__ deg, float* __restrict__ dinv, int n) {
  int i = blockIdx.x * blockDim.x + threadIdx.x;
  if (i < n) dinv[i] = rsqrtf((float)deg[i] + 1.0f);
}

__global__ __launch_bounds__(1024) void scan_exclusive_kernel(const int* __restrict__ deg,
                                                              int* __restrict__ offs, int n) {
  __shared__ int wsum[16];
  __shared__ int carry_s;
  const int tid = threadIdx.x;
  const int lane = tid & 63;
  const int wid = tid >> 6;
  if (tid == 0) carry_s = 0;
  __syncthreads();
  for (int base = 0; base < n; base += 1024) {
    int i = base + tid;
    int v = (i < n) ? deg[i] : 0;
    int incl = v;
#pragma unroll
    for (int d = 1; d < 64; d <<= 1) {
      int t = __shfl_up(incl, d, 64);
      if (lane >= d) incl += t;
    }
    if (lane == 63) wsum[wid] = incl;
    __syncthreads();
    if (wid == 0) {
      int sv = (lane < 16) ? wsum[lane] : 0;
#pragma unroll
      for (int d = 1; d < 16; d <<= 1) {
        int t = __shfl_up(sv, d, 64);
        if (lane >= d) sv += t;
      }
      if (lane < 16) wsum[lane] = sv;
    }
    __syncthreads();
    int woff = (wid > 0) ? wsum[wid - 1] : 0;
    int excl = woff + incl - v;
    int carry = carry_s;
    if (i < n) offs[i] = carry + excl;
    __syncthreads();
    if (tid == 1023) carry_s = carry + excl + v;
    __syncthreads();
  }
  if (tid == 0) offs[n] = carry_s;
}

__global__ void copy_int_kernel(const int* __restrict__ a, int* __restrict__ b, int n) {
  int i = blockIdx.x * blockDim.x + threadIdx.x;
  if (i < n) b[i] = a[i];
}

__global__ void scatter_kernel(const int* __restrict__ row, const int* __restrict__ col,
                               int* __restrict__ cursor, int* __restrict__ csr_row, int E) {
  int i = blockIdx.x * blockDim.x + threadIdx.x;
  if (i < E) {
    int c = col[i];
    int p = atomicAdd(&cursor[c], 1);
    csr_row[p] = row[i];
  }
}

// --------------------- weight prep: fragment ordering ----------------------
// out layout: [(nt*KS + ks)*64 + lane] * 8 + j   (16B contiguous per lane)
__global__ void prep_bfrag_kernel(const float* __restrict__ W, unsigned short* __restrict__ out,
                                  int K, int N) {
  int idx = blockIdx.x * blockDim.x + threadIdx.x;
  int KS = K / 32;
  int total = (N / 16) * KS * 64;
  if (idx >= total) return;
  int lane = idx & 63;
  int t = idx >> 6;
  int ks = t % KS;
  int nt = t / KS;
  int n = nt * 16 + (lane & 15);
  int k0 = ks * 32 + (lane >> 4) * 8;
  unsigned short* o = out + (size_t)idx * 8;
#pragma unroll
  for (int j = 0; j < 8; ++j) o[j] = f2bf(W[(size_t)(k0 + j) * N + n]);
}

// ------------------------------- MFMA GEMM ---------------------------------
// C[M,N](bf16) = A[M,K] @ Bfrag. Block = 4 waves; each wave does 32 rows.
template <int K, int N, bool ABF16>
__global__ __launch_bounds__(256) void mfma_gemm_kernel(const void* __restrict__ Ap,
                                                        const unsigned short* __restrict__ Bfrag,
                                                        unsigned short* __restrict__ Cout, int M) {
  constexpr int KS = K / 32;
  constexpr int NT = N / 16;
  const int lane = threadIdx.x & 63;
  const int wid = threadIdx.x >> 6;
  const int quad = lane >> 4;
  const int lc = lane & 15;
  const int mbase = blockIdx.x * 128 + wid * 32;
  if (mbase >= M) return;

  f32x4 acc[2][NT];
#pragma unroll
  for (int mt = 0; mt < 2; ++mt)
#pragma unroll
    for (int nt = 0; nt < NT; ++nt) acc[mt][nt] = (f32x4){0.f, 0.f, 0.f, 0.f};

  int r0 = mbase + lc;
  int r1 = mbase + 16 + lc;
  if (r0 >= M) r0 = M - 1;
  if (r1 >= M) r1 = M - 1;

#pragma unroll
  for (int ks = 0; ks < KS; ++ks) {
    const int k0 = ks * 32 + quad * 8;
    short8x a[2];
    if constexpr (ABF16) {
      const unsigned short* A = (const unsigned short*)Ap;
      a[0] = *(const short8x*)(A + (size_t)r0 * K + k0);
      a[1] = *(const short8x*)(A + (size_t)r1 * K + k0);
    } else {
      const float* A = (const float*)Ap;
      const float4* p0 = (const float4*)(A + (size_t)r0 * K + k0);
      const float4* p1 = (const float4*)(A + (size_t)r1 * K + k0);
      float4 u0 = p0[0], v0 = p0[1];
      float4 u1 = p1[0], v1 = p1[1];
      short8x t0, t1;
      t0[0] = (short)f2bf(u0.x); t0[1] = (short)f2bf(u0.y);
      t0[2] = (short)f2bf(u0.z); t0[3] = (short)f2bf(u0.w);
      t0[4] = (short)f2bf(v0.x); t0[5] = (short)f2bf(v0.y);
      t0[6] = (short)f2bf(v0.z); t0[7] = (short)f2bf(v0.w);
      t1[0] = (short)f2bf(u1.x); t1[1] = (short)f2bf(u1.y);
      t1[2] = (short)f2bf(u1.z); t1[3] = (short)f2bf(u1.w);
      t1[4] = (short)f2bf(v1.x); t1[5] = (short)f2bf(v1.y);
      t1[6] = (short)f2bf(v1.z); t1[7] = (short)f2bf(v1.w);
      a[0] = t0;
      a[1] = t1;
    }
#pragma unroll
    for (int nt = 0; nt < NT; ++nt) {
      short8x b = *(const short8x*)(Bfrag + (((size_t)nt * KS + ks) * 64 + lane) * 8);
      acc[0][nt] = __builtin_amdgcn_mfma_f32_16x16x32_bf16(a[0], b, acc[0][nt], 0, 0, 0);
      acc[1][nt] = __builtin_amdgcn_mfma_f32_16x16x32_bf16(a[1], b, acc[1][nt], 0, 0, 0);
    }
  }

#pragma unroll
  for (int mt = 0; mt < 2; ++mt)
#pragma unroll
    for (int nt = 0; nt < NT; ++nt)
#pragma unroll
      for (int reg = 0; reg < 4; ++reg) {
        int row = mbase + mt * 16 + quad * 4 + reg;
        if (row < M) Cout[(size_t)row * N + nt * 16 + lc] = f2bf(acc[mt][nt][reg]);
      }
}

// --------------------------- aggregation (bf16) ----------------------------
template <int F>
__global__ void agg_bn_relu_kernel(const unsigned short* __restrict__ xw,
                                   const int* __restrict__ offs, const int* __restrict__ rows,
                                   const float* __restrict__ dinv, const float* __restrict__ bias,
                                   const float* __restrict__ gamma, const float* __restrict__ beta,
                                   const float* __restrict__ mean, const float* __restrict__ var,
                                   unsigned short* __restrict__ out) {
  const int i = blockIdx.x;
  const int f = threadIdx.x;
  const float di = dinv[i];
  const int s = offs[i], e = offs[i + 1];
  float acc = 0.f;
  int t = s;
  for (; t + 4 <= e; t += 4) {
    int r0 = rows[t], r1 = rows[t + 1], r2 = rows[t + 2], r3 = rows[t + 3];
    float w0 = dinv[r0], w1 = dinv[r1], w2 = dinv[r2], w3 = dinv[r3];
    acc += w0 * bf2f(xw[(size_t)r0 * F + f]) + w1 * bf2f(xw[(size_t)r1 * F + f]) +
           w2 * bf2f(xw[(size_t)r2 * F + f]) + w3 * bf2f(xw[(size_t)r3 * F + f]);
  }
  for (; t < e; ++t) {
    int r = rows[t];
    acc += dinv[r] * bf2f(xw[(size_t)r * F + f]);
  }
  float v = di * acc + di * di * bf2f(xw[(size_t)i * F + f]) + bias[f];
  v = (v - mean[f]) * rsqrtf(var[f] + 1e-5f) * gamma[f] + beta[f];
  out[(size_t)i * F + f] = f2bf(fmaxf(v, 0.f));
}

// ------------------------------- edge head ---------------------------------
// Per wave: 16 pairs. A = (z[src]||z[dst]) bf16, B = hW1 fragments (in regs).
// Fused relu + dot(hW2) + sigmoid.
__global__ __launch_bounds__(256) void head_mfma_kernel(
    const unsigned short* __restrict__ z, const int* __restrict__ src,
    const int* __restrict__ dst, const unsigned short* __restrict__ bfragH,
    const float* __restrict__ hb1, const float* __restrict__ hw2,
    const float* __restrict__ hb2, float* __restrict__ out, int P) {
  const int lane = threadIdx.x & 63;
  const int quad = lane >> 4;
  const int lc = lane & 15;

  short8x bf[4][4];  // [nt][ks]
#pragma unroll
  for (int nt = 0; nt < 4; ++nt)
#pragma unroll
    for (int ks = 0; ks < 4; ++ks)
      bf[nt][ks] = *(const short8x*)(bfragH + (((size_t)nt * 4 + ks) * 64 + lane) * 8);

  float b1v[4], w2v[4];
#pragma unroll
  for (int nt = 0; nt < 4; ++nt) {
    b1v[nt] = hb1[nt * 16 + lc];
    w2v[nt] = hw2[nt * 16 + lc];
  }
  const float bias2 = hb2[0];

  const int nchunks = (P + 15) / 16;
  const int gw = blockIdx.x * 4 + (threadIdx.x >> 6);
  const int nw = gridDim.x * 4;

  for (int ch = gw; ch < nchunks; ch += nw) {
    int p = ch * 16 + lc;
    int pc = p < P ? p : P - 1;
    int s = src[pc], d = dst[pc];
    const unsigned short* zs = z + (size_t)s * 64;
    const unsigned short* zd = z + (size_t)d * 64;
    short8x a[4];
    a[0] = *(const short8x*)(zs + quad * 8);
    a[1] = *(const short8x*)(zs + 32 + quad * 8);
    a[2] = *(const short8x*)(zd + quad * 8);
    a[3] = *(const short8x*)(zd + 32 + quad * 8);

    f32x4 acc[4];
#pragma unroll
    for (int nt = 0; nt < 4; ++nt) acc[nt] = (f32x4){0.f, 0.f, 0.f, 0.f};
#pragma unroll
    for (int nt = 0; nt < 4; ++nt)
#pragma unroll
      for (int t = 0; t < 4; ++t)
        acc[nt] = __builtin_amdgcn_mfma_f32_16x16x32_bf16(a[t], bf[nt][t], acc[nt], 0, 0, 0);

    float part[4];
#pragma unroll
    for (int reg = 0; reg < 4; ++reg) {
      float sum = 0.f;
#pragma unroll
      for (int nt = 0; nt < 4; ++nt) sum += fmaxf(acc[nt][reg] + b1v[nt], 0.f) * w2v[nt];
      part[reg] = sum;
    }
#pragma unroll
    for (int m = 1; m < 16; m <<= 1) {
#pragma unroll
      for (int reg = 0; reg < 4; ++reg) part[reg] += __shfl_xor(part[reg], m, 64);
    }
    if (lc == 0) {
      int pbase = ch * 16 + quad * 4;
      float4 o;
      o.x = 1.0f / (1.0f + __expf(-(part[0] + bias2)));
      o.y = 1.0f / (1.0f + __expf(-(part[1] + bias2)));
      o.z = 1.0f / (1.0f + __expf(-(part[2] + bias2)));
      o.w = 1.0f / (1.0f + __expf(-(part[3] + bias2)));
      if (pbase + 3 < P) {
        *(float4*)(out + pbase) = o;
      } else {
        float ov[4] = {o.x, o.y, o.z, o.w};
        for (int reg = 0; reg < 4; ++reg)
          if (pbase + reg < P) out[pbase + reg] = ov[reg];
      }
    }
  }
}

// ------------------------------- launcher ----------------------------------

extern "C" void kernel_launch(void* const* d_in, const int* in_sizes, int n_in,
                              void* d_out, int out_size, void* d_ws, size_t ws_size,
                              hipStream_t stream) {
  const float* x = (const float*)d_in[0];
  const int* ei = (const int*)d_in[1];
  const int* src = (const int*)d_in[2];
  const int* dst = (const int*)d_in[3];
  const float* W1 = (const float*)d_in[4];
  const float* b1 = (const float*)d_in[5];
  const float* g1 = (const float*)d_in[6];
  const float* be1 = (const float*)d_in[7];
  const float* mu1 = (const float*)d_in[8];
  const float* va1 = (const float*)d_in[9];
  const float* W2 = (const float*)d_in[10];
  const float* b2 = (const float*)d_in[11];
  const float* g2 = (const float*)d_in[12];
  const float* be2 = (const float*)d_in[13];
  const float* mu2 = (const float*)d_in[14];
  const float* va2 = (const float*)d_in[15];
  const float* hW1 = (const float*)d_in[16];
  const float* hb1 = (const float*)d_in[17];
  const float* hW2 = (const float*)d_in[18];
  const float* hb2 = (const float*)d_in[19];
  float* out = (float*)d_out;

  const int N = in_sizes[0] / 512;
  const int E = in_sizes[1] / 2;
  const int P = in_sizes[2];
  const int* row = ei;
  const int* col = ei + E;

  char* wp = (char*)d_ws;
  auto alloc = [&](size_t bytes) {
    char* p = wp;
    wp += (bytes + 255) & ~(size_t)255;
    return p;
  };
  unsigned short* xw1 = (unsigned short*)alloc((size_t)N * 128 * 2);
  unsigned short* h = (unsigned short*)alloc((size_t)N * 128 * 2);
  unsigned short* xw2 = (unsigned short*)alloc((size_t)N * 64 * 2);
  unsigned short* z = (unsigned short*)alloc((size_t)N * 64 * 2);
  float* dinv = (float*)alloc((size_t)N * 4);
  int* deg = (int*)alloc((size_t)N * 4);
  int* offs = (int*)alloc((size_t)(N + 1) * 4);
  int* cursor = (int*)alloc((size_t)N * 4);
  int* csr_row = (int*)alloc((size_t)E * 4);
  unsigned short* bfW1 = (unsigned short*)alloc(512 * 128 * 2);
  unsigned short* bfW2 = (unsigned short*)alloc(128 * 64 * 2);
  unsigned short* bfH = (unsigned short*)alloc(128 * 64 * 2);
  (void)ws_size;
  (void)n_in;
  (void)out_size;

  // graph structure
  hipLaunchKernelGGL(zero_int_kernel, dim3((N + 255) / 256), dim3(256), 0, stream, deg, N);
  hipLaunchKernelGGL(degree_hist_kernel, dim3((E + 255) / 256), dim3(256), 0, stream, col, deg, E);
  hipLaunchKernelGGL(dinv_kernel, dim3((N + 255) / 256), dim3(256), 0, stream, deg, dinv, N);
  hipLaunchKernelGGL(scan_exclusive_kernel, dim3(1), dim3(1024), 0, stream, deg, offs, N);
  hipLaunchKernelGGL(copy_int_kernel, dim3((N + 255) / 256), dim3(256), 0, stream, offs, cursor, N);
  hipLaunchKernelGGL(scatter_kernel, dim3((E + 255) / 256), dim3(256), 0, stream, row, col, cursor,
                     csr_row, E);

  // weight fragment prep
  hipLaunchKernelGGL(prep_bfrag_kernel, dim3((8 * 16 * 64 + 255) / 256), dim3(256), 0, stream, W1,
                     bfW1, 512, 128);
  hipLaunchKernelGGL(prep_bfrag_kernel, dim3((4 * 4 * 64 + 255) / 256), dim3(256), 0, stream, W2,
                     bfW2, 128, 64);
  hipLaunchKernelGGL(prep_bfrag_kernel, dim3((4 * 4 * 64 + 255) / 256), dim3(256), 0, stream, hW1,
                     bfH, 128, 64);

  // layer 1
  hipLaunchKernelGGL((mfma_gemm_kernel<512, 128, false>), dim3((N + 127) / 128), dim3(256), 0,
                     stream, x, bfW1, xw1, N);
  hipLaunchKernelGGL((agg_bn_relu_kernel<128>), dim3(N), dim3(128), 0, stream, xw1, offs, csr_row,
                     dinv, b1, g1, be1, mu1, va1, h);

  // layer 2
  hipLaunchKernelGGL((mfma_gemm_kernel<128, 64, true>), dim3((N + 127) / 128), dim3(256), 0, stream,
                     h, bfW2, xw2, N);
  hipLaunchKernelGGL((agg_bn_relu_kernel<64>), dim3(N), dim3(64), 0, stream, xw2, offs, csr_row,
                     dinv, b2, g2, be2, mu2, va2, z);

  // edge head
  hipLaunchKernelGGL(head_mfma_kernel, dim3(2048), dim3(256), 0, stream, z, src, dst, bfH, hb1,
                     hW2, hb2, out, P);
}